// Round 7
// baseline (310.595 us; speedup 1.0000x reference)
//
#include <hip/hip_runtime.h>
#include <hip/hip_bf16.h>
#include <stdint.h>

// Problem constants (fixed-shape problem)
#define B 512
#define N 100000
#define D 128
#define INV_T (1.0f / 0.07f)

// Masks are int32 (0/1). int_mask is a SUBSET of bg_mask (reference:
// int = (bg & close) | diag, bg = bg | diag), so we stream ONLY bg_mask
// and gather im[] at the ~0.5% hit positions in phase 2.
#define ROW_U4   (N / 4)         // 25000 uint4 groups per mask row
#define NBX      4               // blocks per row
#define BLK_U4   (ROW_U4 / NBX)  // 6250 uint4 groups per block (exact)
#define NBLOCKS  (NBX * B)       // 2048
#define QCAP     1024            // queue entries (expected ~130/block)

// Early-out group processor: 3 ORs + 1 branch for the ~98% all-zero case.
#define PROC(av, gidx)                                                       \
{                                                                            \
    uint32_t any_ = (av).x | (av).y | (av).z | (av).w;                       \
    if (any_) {                                                              \
        uint32_t aw_[4] = {(av).x, (av).y, (av).z, (av).w};                  \
        _Pragma("unroll")                                                    \
        for (int j_ = 0; j_ < 4; ++j_) {                                     \
            if (aw_[j_]) {                                                   \
                int slot_ = atomicAdd(&qcount, 1);                           \
                if (slot_ < QCAP) queue[slot_] = (gidx) * 4 + j_;            \
            }                                                                \
        }                                                                    \
    }                                                                        \
}

// ---------------------------------------------------------------- main scan
// Grid: (NBX, B). Block: 256 threads.
// Wave 0 normalizes codes[b] into LDS (concurrent with phase-1 streaming).
// Phase 1: stream this block's 6250-uint4 slice of bg, 12 coalesced 16B
//          loads in flight per thread, early-out on all-zero groups.
// Phase 2: half-wave (32 lanes x float4) per bank row, 2-deep row pipeline;
//          lane 0 gathers im[b*N+n]; dot -> exp -> acc1 always, acc2 iff im.
// Epilogue: last block (ticket) reduces d1/d2 -> out (fused finalize).
__global__ void scan_kernel(const float* __restrict__ codes,
                            const float* __restrict__ bank,
                            const uint32_t* __restrict__ bg,
                            const uint32_t* __restrict__ im,
                            float* __restrict__ d1,
                            float* __restrict__ d2,
                            int* __restrict__ ticket,
                            float* __restrict__ out) {
    __shared__ float vrow[D];
    __shared__ int   queue[QCAP];
    __shared__ int   qcount;
    __shared__ int   amLast;
    __shared__ float red[4];

    const int b   = blockIdx.y;
    const int tid = threadIdx.x;

    if (tid == 0) qcount = 0;
    __syncthreads();                       // qcount ready before PROC atomics

    // ---- wave 0: normalize codes row into vrow (other waves stream ahead)
    if (tid < 64) {
        float x0 = codes[b * D + tid];
        float x1 = codes[b * D + tid + 64];
        float s = x0 * x0 + x1 * x1;
        #pragma unroll
        for (int off = 32; off; off >>= 1) s += __shfl_xor(s, off, 64);
        float rn = 1.0f / sqrtf(s);
        vrow[tid]      = x0 * rn;
        vrow[tid + 64] = x1 * rn;
    }

    // ---- phase 1: 6250 = 24*256 + 106; two rounds of 12 batched loads
    const uint4* bgu = (const uint4*)(bg + (size_t)b * N);
    const int start = blockIdx.x * BLK_U4;
    const int s0 = start + tid;

    #pragma unroll
    for (int r = 0; r < 2; ++r) {
        const int g = s0 + r * 3072;
        uint4 x0  = bgu[g];
        uint4 x1  = bgu[g + 256];
        uint4 x2  = bgu[g + 512];
        uint4 x3  = bgu[g + 768];
        uint4 x4  = bgu[g + 1024];
        uint4 x5  = bgu[g + 1280];
        uint4 x6  = bgu[g + 1536];
        uint4 x7  = bgu[g + 1792];
        uint4 x8  = bgu[g + 2048];
        uint4 x9  = bgu[g + 2304];
        uint4 x10 = bgu[g + 2560];
        uint4 x11 = bgu[g + 2816];
        PROC(x0,  g);
        PROC(x1,  g + 256);
        PROC(x2,  g + 512);
        PROC(x3,  g + 768);
        PROC(x4,  g + 1024);
        PROC(x5,  g + 1280);
        PROC(x6,  g + 1536);
        PROC(x7,  g + 1792);
        PROC(x8,  g + 2048);
        PROC(x9,  g + 2304);
        PROC(x10, g + 2560);
        PROC(x11, g + 2816);
    }
    if (tid < 106) {
        const int g = start + 6144 + tid;
        uint4 t0 = bgu[g];
        PROC(t0, g);
    }
    __syncthreads();

    // ---- phase 2
    const int cnt  = qcount;               // expected ~130 << QCAP
    const int wave = tid >> 6;
    const int lane = tid & 63;
    const int half = lane >> 5;            // half-wave owns one bank row
    const int l32  = lane & 31;

    float acc1 = 0.0f, acc2 = 0.0f;
    const float4 vv = ((const float4*)vrow)[l32];   // 32 lanes x 4f = 128 f

    for (int base = wave * 2; base < cnt; base += 16) {
        int idx0 = base + half;
        int idx1 = base + 8 + half;
        float4 bv0, bv1;
        uint32_t iv0 = 0, iv1 = 0;
        bool ok0 = (idx0 < cnt), ok1 = (idx1 < cnt);
        if (ok0) {                         // issue gathers up front
            int n0 = queue[idx0];
            bv0 = ((const float4*)(bank + (size_t)n0 * D))[l32];
            if (l32 == 0) iv0 = im[(size_t)b * N + n0];
        }
        if (ok1) {
            int n1 = queue[idx1];
            bv1 = ((const float4*)(bank + (size_t)n1 * D))[l32];
            if (l32 == 0) iv1 = im[(size_t)b * N + n1];
        }
        if (ok0) {
            float p = vv.x*bv0.x + vv.y*bv0.y + vv.z*bv0.z + vv.w*bv0.w;
            #pragma unroll
            for (int off = 16; off; off >>= 1) p += __shfl_xor(p, off, 64);
            float e = __expf(p * INV_T);
            if (l32 == 0) {
                acc1 += e;
                if (iv0) acc2 += e;
            }
        }
        if (ok1) {
            float p = vv.x*bv1.x + vv.y*bv1.y + vv.z*bv1.z + vv.w*bv1.w;
            #pragma unroll
            for (int off = 16; off; off >>= 1) p += __shfl_xor(p, off, 64);
            float e = __expf(p * INV_T);
            if (l32 == 0) {
                acc1 += e;
                if (iv1) acc2 += e;
            }
        }
    }
    acc1 += __shfl_xor(acc1, 32, 64);
    acc2 += __shfl_xor(acc2, 32, 64);
    if (lane == 0) {
        if (acc1 != 0.0f) atomicAdd(&d1[b], acc1);
        if (acc2 != 0.0f) atomicAdd(&d2[b], acc2);
    }

    // ---- fused finalize: last block to finish reduces d1/d2 into out
    __threadfence();                       // make d1/d2 atomics visible
    if (tid == 0) {
        int t = atomicAdd(ticket, 1);
        amLast = (t == NBLOCKS - 1);
    }
    __syncthreads();
    if (!amLast) return;

    float val = 0.0f;
    for (int i = tid; i < B; i += 256) {
        float x1 = atomicAdd(&d1[i], 0.0f);   // coherent device-scope read
        float x2 = atomicAdd(&d2[i], 0.0f);
        val += logf(x1) - logf(x2);
    }
    #pragma unroll
    for (int off = 32; off; off >>= 1) val += __shfl_xor(val, off, 64);
    if ((tid & 63) == 0) red[tid >> 6] = val;
    __syncthreads();
    if (tid == 0) {
        float s = red[0] + red[1] + red[2] + red[3];
        out[0] = s / (float)B;
    }
}

extern "C" void kernel_launch(void* const* d_in, const int* in_sizes, int n_in,
                              void* d_out, int out_size, void* d_ws, size_t ws_size,
                              hipStream_t stream) {
    const float*    codes = (const float*)d_in[0];
    const float*    bank  = (const float*)d_in[1];
    const uint32_t* bg    = (const uint32_t*)d_in[2];
    const uint32_t* im    = (const uint32_t*)d_in[3];
    float*          out   = (float*)d_out;

    // workspace layout: d1 (B f32), d2 (B f32), ticket (1 int)
    float* d1 = (float*)d_ws;
    float* d2 = d1 + B;
    int* ticket = (int*)(d2 + B);

    hipMemsetAsync(d1, 0, (2 * B + 1) * sizeof(float), stream);
    scan_kernel<<<dim3(NBX, B), 256, 0, stream>>>(codes, bank, bg, im,
                                                  d1, d2, ticket, out);
}

// Round 8
// 61.315 us; speedup vs baseline: 5.0656x; 5.0656x over previous
//
#include <hip/hip_runtime.h>
#include <hip/hip_bf16.h>
#include <stdint.h>

// Problem constants (fixed-shape problem)
#define B 512
#define N 100000
#define D 128
#define INV_T (1.0f / 0.07f)

// Masks are int32 (0/1). int_mask is a SUBSET of bg_mask (reference:
// int = (bg & close) | diag, bg = bg | diag), so we stream ONLY bg_mask
// and gather im[] at the ~0.5% hit positions in phase 2.
#define ROW_U4   (N / 4)         // 25000 uint4 groups per mask row
#define NBX      8               // blocks per row
#define BLK_U4   (ROW_U4 / NBX)  // 3125 uint4 groups per block (exact)
#define QCAP     1024            // queue entries (expected ~65/block)

// Early-out group processor: 3 ORs + 1 branch for the ~98% all-zero case.
#define PROC(av, gidx)                                                       \
{                                                                            \
    uint32_t any_ = (av).x | (av).y | (av).z | (av).w;                       \
    if (any_) {                                                              \
        uint32_t aw_[4] = {(av).x, (av).y, (av).z, (av).w};                  \
        _Pragma("unroll")                                                    \
        for (int j_ = 0; j_ < 4; ++j_) {                                     \
            if (aw_[j_]) {                                                   \
                int slot_ = atomicAdd(&qcount, 1);                           \
                if (slot_ < QCAP) queue[slot_] = (gidx) * 4 + j_;            \
            }                                                                \
        }                                                                    \
    }                                                                        \
}

// ---------------------------------------------------------------- main scan
// Grid: (NBX, B). Block: 256 threads.
// Wave 0 normalizes codes[b] into LDS (concurrent with phase-1 streaming).
// Phase 1: stream this block's 3125-uint4 slice of bg only, 12 loads in
//          flight per thread (2 rounds of 6), early-out on all-zero groups.
// Phase 2: half-wave (32 lanes x float4) per bank row, 2-deep row pipeline;
//          lane 0 gathers im[b*N+n]; dot -> exp -> acc1 always, acc2 iff im.
// Output: plain store of per-block partials (block owns slot b*NBX+x) --
//         no atomics, no zero-init, no fences.
__global__ void scan_kernel(const float* __restrict__ codes,
                            const float* __restrict__ bank,
                            const uint32_t* __restrict__ bg,
                            const uint32_t* __restrict__ im,
                            float* __restrict__ d1p,
                            float* __restrict__ d2p) {
    __shared__ float vrow[D];
    __shared__ int   queue[QCAP];
    __shared__ int   qcount;

    const int b   = blockIdx.y;
    const int tid = threadIdx.x;

    if (tid == 0) qcount = 0;
    __syncthreads();                       // qcount ready before PROC atomics

    // ---- wave 0: normalize codes row into vrow (other waves stream ahead)
    if (tid < 64) {
        float x0 = codes[b * D + tid];
        float x1 = codes[b * D + tid + 64];
        float s = x0 * x0 + x1 * x1;
        #pragma unroll
        for (int off = 32; off; off >>= 1) s += __shfl_xor(s, off, 64);
        float rn = 1.0f / sqrtf(s);
        vrow[tid]      = x0 * rn;
        vrow[tid + 64] = x1 * rn;
    }

    // ---- phase 1: 3125 = 12*256 + 53, one stream only
    const uint4* bgu = (const uint4*)(bg + (size_t)b * N);
    const int start = blockIdx.x * BLK_U4;
    const int gA = start + tid;            // round A base
    const int gB = gA + 1536;              // round B base

    uint4 a0 = bgu[gA];
    uint4 a1 = bgu[gA + 256];
    uint4 a2 = bgu[gA + 512];
    uint4 a3 = bgu[gA + 768];
    uint4 a4 = bgu[gA + 1024];
    uint4 a5 = bgu[gA + 1280];
    uint4 b0 = bgu[gB];
    uint4 b1 = bgu[gB + 256];
    uint4 b2 = bgu[gB + 512];
    uint4 b3 = bgu[gB + 768];
    uint4 b4 = bgu[gB + 1024];
    uint4 b5 = bgu[gB + 1280];

    PROC(a0, gA);
    PROC(a1, gA + 256);
    PROC(a2, gA + 512);
    PROC(a3, gA + 768);
    PROC(a4, gA + 1024);
    PROC(a5, gA + 1280);

    uint4 tl;
    const int gT = start + 3072 + tid;
    if (tid < 53) tl = bgu[gT];

    PROC(b0, gB);
    PROC(b1, gB + 256);
    PROC(b2, gB + 512);
    PROC(b3, gB + 768);
    PROC(b4, gB + 1024);
    PROC(b5, gB + 1280);

    if (tid < 53) PROC(tl, gT);
    __syncthreads();

    // ---- phase 2
    const int cnt  = qcount;               // expected ~65 << QCAP
    const int wave = tid >> 6;
    const int lane = tid & 63;
    const int half = lane >> 5;            // half-wave owns one bank row
    const int l32  = lane & 31;

    float acc1 = 0.0f, acc2 = 0.0f;
    const float4 vv = ((const float4*)vrow)[l32];   // 32 lanes x 4f = 128 f

    for (int base = wave * 2; base < cnt; base += 16) {
        int idx0 = base + half;
        int idx1 = base + 8 + half;
        float4 bv0, bv1;
        uint32_t iv0 = 0, iv1 = 0;
        bool ok0 = (idx0 < cnt), ok1 = (idx1 < cnt);
        if (ok0) {                         // issue gathers up front
            int n0 = queue[idx0];
            bv0 = ((const float4*)(bank + (size_t)n0 * D))[l32];
            if (l32 == 0) iv0 = im[(size_t)b * N + n0];
        }
        if (ok1) {
            int n1 = queue[idx1];
            bv1 = ((const float4*)(bank + (size_t)n1 * D))[l32];
            if (l32 == 0) iv1 = im[(size_t)b * N + n1];
        }
        if (ok0) {
            float p = vv.x*bv0.x + vv.y*bv0.y + vv.z*bv0.z + vv.w*bv0.w;
            #pragma unroll
            for (int off = 16; off; off >>= 1) p += __shfl_xor(p, off, 64);
            float e = __expf(p * INV_T);
            if (l32 == 0) {
                acc1 += e;
                if (iv0) acc2 += e;
            }
        }
        if (ok1) {
            float p = vv.x*bv1.x + vv.y*bv1.y + vv.z*bv1.z + vv.w*bv1.w;
            #pragma unroll
            for (int off = 16; off; off >>= 1) p += __shfl_xor(p, off, 64);
            float e = __expf(p * INV_T);
            if (l32 == 0) {
                acc1 += e;
                if (iv1) acc2 += e;
            }
        }
    }
    acc1 += __shfl_xor(acc1, 32, 64);
    acc2 += __shfl_xor(acc2, 32, 64);

    // combine the 4 waves' partials via LDS (reuse queue space)
    __shared__ float wred[8];
    if (lane == 0) { wred[wave] = acc1; wred[wave + 4] = acc2; }
    __syncthreads();
    if (tid == 0) {
        float s1 = wred[0] + wred[1] + wred[2] + wred[3];
        float s2 = wred[4] + wred[5] + wred[6] + wred[7];
        d1p[b * NBX + blockIdx.x] = s1;    // block owns this slot
        d2p[b * NBX + blockIdx.x] = s2;
    }
}

// ---------------------------------------------------------------- finalize
__global__ void finalize_kernel(const float* __restrict__ d1p,
                                const float* __restrict__ d2p,
                                float* __restrict__ out) {
    __shared__ float red[8];
    const int t = threadIdx.x;    // 512 threads, one per row
    float s1 = 0.0f, s2 = 0.0f;
    #pragma unroll
    for (int j = 0; j < NBX; ++j) {
        s1 += d1p[t * NBX + j];
        s2 += d2p[t * NBX + j];
    }
    float val = logf(s1) - logf(s2);
    #pragma unroll
    for (int off = 32; off; off >>= 1) val += __shfl_xor(val, off, 64);
    if ((t & 63) == 0) red[t >> 6] = val;
    __syncthreads();
    if (t == 0) {
        float s = 0.0f;
        #pragma unroll
        for (int i = 0; i < 8; ++i) s += red[i];
        out[0] = s / (float)B;
    }
}

extern "C" void kernel_launch(void* const* d_in, const int* in_sizes, int n_in,
                              void* d_out, int out_size, void* d_ws, size_t ws_size,
                              hipStream_t stream) {
    const float*    codes = (const float*)d_in[0];
    const float*    bank  = (const float*)d_in[1];
    const uint32_t* bg    = (const uint32_t*)d_in[2];
    const uint32_t* im    = (const uint32_t*)d_in[3];
    float*          out   = (float*)d_out;

    // workspace layout: d1p (B*NBX f32), d2p (B*NBX f32)
    float* d1p = (float*)d_ws;
    float* d2p = d1p + B * NBX;

    scan_kernel<<<dim3(NBX, B), 256, 0, stream>>>(codes, bank, bg, im, d1p, d2p);
    finalize_kernel<<<1, B, 0, stream>>>(d1p, d2p, out);
}